// Round 2
// baseline (806.727 us; speedup 1.0000x reference)
//
#include <hip/hip_runtime.h>
#include <hip/hip_bf16.h>
#include <math.h>

// Problem constants
#define B_    16
#define CE_   128
#define CB_   256
#define H_    56
#define W_    56
#define NH_   8
#define WS_   7
#define HD_   32
#define NWIN_ 49      // WS*WS
#define HW_   3136    // H*W
#define M_    50176   // B*H*W rows
#define HID_  1024

typedef short bf16x8 __attribute__((ext_vector_type(8)));
typedef float f32x4  __attribute__((ext_vector_type(4)));

__device__ __forceinline__ float waveRedSum(float v) {
#pragma unroll
  for (int off = 32; off; off >>= 1) v += __shfl_xor(v, off, 64);
  return v;
}

// ---------------------------------------------------------------------------
// Per-batch mean/rstd over (C,H,W) of x_edge.  16 blocks x 256 threads.
__global__ void k_stats(const float* __restrict__ xe, float* __restrict__ stats) {
  int b = blockIdx.x;
  const float4* p = (const float4*)(xe + (size_t)b * 401408);
  float s = 0.f, s2 = 0.f;
  for (int i = threadIdx.x; i < 401408 / 4; i += 256) {
    float4 v = p[i];
    s  += v.x + v.y + v.z + v.w;
    s2 += v.x * v.x + v.y * v.y + v.z * v.z + v.w * v.w;
  }
  s = waveRedSum(s); s2 = waveRedSum(s2);
  __shared__ float aux[8];
  int wave = threadIdx.x >> 6, lane = threadIdx.x & 63;
  if (lane == 0) { aux[wave] = s; aux[4 + wave] = s2; }
  __syncthreads();
  if (threadIdx.x == 0) {
    float S  = aux[0] + aux[1] + aux[2] + aux[3];
    float S2 = aux[4] + aux[5] + aux[6] + aux[7];
    float mean = S / 401408.0f;
    float var  = S2 / 401408.0f - mean * mean;
    stats[b * 2] = mean;
    stats[b * 2 + 1] = rsqrtf(var + 1e-5f);
  }
}

// ---------------------------------------------------------------------------
// Normalize x_edge (per-element affine), emit bf16 A matrix in WINDOWED row
// order: row m = wb*49 + p, cols = 128 channels.  1024 blocks (one/window).
__global__ void k_prep_edge(const float* __restrict__ xe,
                            const float* __restrict__ we,
                            const float* __restrict__ be,
                            const float* __restrict__ stats,
                            __hip_bfloat16* __restrict__ Ae) {
  int wb = blockIdx.x;
  int b = wb >> 6, rem = wb & 63;
  int h0 = (rem >> 3) * 7, w0 = (rem & 7) * 7;
  float mean = stats[b * 2], rstd = stats[b * 2 + 1];
  __shared__ __hip_bfloat16 t[49 * 130];  // [p][c], pad 130 to break bank stride
  for (int idx = threadIdx.x; idx < 128 * 49; idx += 256) {
    int c = idx / 49, p = idx % 49;
    int h = h0 + p / 7, w = w0 + p % 7;
    int off = (c * 56 + h) * 56 + w;
    float v = xe[(size_t)b * 401408 + off];
    t[p * 130 + c] = __float2bfloat16((v - mean) * rstd * we[off] + be[off]);
  }
  __syncthreads();
  __hip_bfloat16* dst = Ae + (size_t)wb * 49 * 128;
  for (int idx = threadIdx.x; idx < 49 * 128; idx += 256) {
    int p = idx >> 7, c = idx & 127;
    dst[idx] = t[p * 130 + c];
  }
}

// ---------------------------------------------------------------------------
// Row LayerNorm over 256 channels; one wave per row, 4 rows/block.
// PERM=true: write rows in windowed order (for x_body -> KV path).
template <bool PERM>
__global__ void k_ln_rows(const float* __restrict__ x,
                          const float* __restrict__ w,
                          const float* __restrict__ bia,
                          __hip_bfloat16* __restrict__ out) {
  int row = blockIdx.x * 4 + (threadIdx.x >> 6);
  int lane = threadIdx.x & 63;
  float4 xv = *(const float4*)(x + (size_t)row * 256 + lane * 4);
  float s  = xv.x + xv.y + xv.z + xv.w;
  float s2 = xv.x * xv.x + xv.y * xv.y + xv.z * xv.z + xv.w * xv.w;
  s = waveRedSum(s); s2 = waveRedSum(s2);
  float mean = s * (1.0f / 256.0f);
  float var  = s2 * (1.0f / 256.0f) - mean * mean;
  float rstd = rsqrtf(var + 1e-5f);
  int orow = row;
  if (PERM) {
    int b = row / 3136, hw = row % 3136;
    int h = hw / 56, ww = hw % 56;
    orow = (b * 64 + (h / 7) * 8 + (ww / 7)) * 49 + (h % 7) * 7 + (ww % 7);
  }
  float4 wv = *(const float4*)(w + lane * 4);
  float4 bv = *(const float4*)(bia + lane * 4);
  union { __hip_bfloat16 h[4]; uint2 u; } pk;
  pk.h[0] = __float2bfloat16((xv.x - mean) * rstd * wv.x + bv.x);
  pk.h[1] = __float2bfloat16((xv.y - mean) * rstd * wv.y + bv.y);
  pk.h[2] = __float2bfloat16((xv.z - mean) * rstd * wv.z + bv.z);
  pk.h[3] = __float2bfloat16((xv.w - mean) * rstd * wv.w + bv.w);
  *(uint2*)(out + (size_t)orow * 256 + lane * 4) = pk.u;
}

// ---------------------------------------------------------------------------
// MFMA GEMM:  C(MxN) = A(MxK,bf16) * W(NxK,fp32->bf16)^T   with epilogues.
// 128x128 tile, BK=32, 256 threads (4 waves, each 64x64 via 4x4 16x16 frags).
// EPI: 0 store bf16 | 1 scale+bf16 | 2 proj(+bias+resid, permute rows, f32)
//      3 bias+gelu bf16 | 4 bias+resid f32
template <int EPI>
__launch_bounds__(256)
__global__ void gemm_bt(const __hip_bfloat16* __restrict__ A,
                        const float* __restrict__ Bw,
                        int M, int N, int K,
                        __hip_bfloat16* __restrict__ outb,
                        float* __restrict__ outf,
                        const float* __restrict__ bias,
                        const float* __restrict__ resid,
                        float scale) {
  // LDS layout [kquad][row][8] so fragment reads are contiguous 16B
  __shared__ __hip_bfloat16 As[4 * 128 * 8];
  __shared__ __hip_bfloat16 Bs[4 * 128 * 8];
  const int tid  = threadIdx.x;
  const int lane = tid & 63;
  const int wave = tid >> 6;
  const int quad = lane >> 4;
  const int lm   = lane & 15;
  const int wm   = (wave & 1) << 6;
  const int wn   = (wave >> 1) << 6;
  const int n0   = blockIdx.x * 128;
  const int m0   = blockIdx.y * 128;

  f32x4 acc[4][4];
#pragma unroll
  for (int i = 0; i < 4; ++i)
#pragma unroll
    for (int j = 0; j < 4; ++j)
#pragma unroll
      for (int r = 0; r < 4; ++r) acc[i][j][r] = 0.f;

  for (int k0 = 0; k0 < K; k0 += 32) {
    // stage A tile: 128 rows x 32 k (bf16), 16B per thread x 2 passes
#pragma unroll
    for (int p = 0; p < 2; ++p) {
      int lin = p * 256 + tid;
      int r = lin >> 2, q = lin & 3;
      uint4 v = *(const uint4*)(A + (size_t)(m0 + r) * K + k0 + q * 8);
      *(uint4*)&As[(q * 128 + r) * 8] = v;
    }
    // stage B tile: 128 rows x 32 k fp32 -> bf16, 4 floats/thread x 4 passes
#pragma unroll
    for (int p = 0; p < 4; ++p) {
      int lin = p * 256 + tid;
      int r = lin >> 3, f = lin & 7;
      float4 v = *(const float4*)(Bw + (size_t)(n0 + r) * K + k0 + f * 4);
      union { __hip_bfloat16 h[4]; uint2 u; } pk;
      pk.h[0] = __float2bfloat16(v.x);
      pk.h[1] = __float2bfloat16(v.y);
      pk.h[2] = __float2bfloat16(v.z);
      pk.h[3] = __float2bfloat16(v.w);
      *(uint2*)&Bs[((f >> 1) * 128 + r) * 8 + (f & 1) * 4] = pk.u;
    }
    __syncthreads();
    bf16x8 af[4], bfr[4];
#pragma unroll
    for (int i = 0; i < 4; ++i)
      af[i] = *(const bf16x8*)&As[(quad * 128 + wm + i * 16 + lm) * 8];
#pragma unroll
    for (int j = 0; j < 4; ++j)
      bfr[j] = *(const bf16x8*)&Bs[(quad * 128 + wn + j * 16 + lm) * 8];
#pragma unroll
    for (int i = 0; i < 4; ++i)
#pragma unroll
      for (int j = 0; j < 4; ++j)
        acc[i][j] = __builtin_amdgcn_mfma_f32_16x16x32_bf16(af[i], bfr[j], acc[i][j], 0, 0, 0);
    __syncthreads();
  }

#pragma unroll
  for (int i = 0; i < 4; ++i) {
#pragma unroll
    for (int j = 0; j < 4; ++j) {
#pragma unroll
      for (int r = 0; r < 4; ++r) {
        int gm = m0 + wm + i * 16 + quad * 4 + r;
        int gn = n0 + wn + j * 16 + lm;
        float v = acc[i][j][r];
        if constexpr (EPI == 0) {
          outb[(size_t)gm * N + gn] = __float2bfloat16(v);
        } else if constexpr (EPI == 1) {
          outb[(size_t)gm * N + gn] = __float2bfloat16(v * scale);
        } else if constexpr (EPI == 2) {
          // windowed row -> natural row, add proj bias + x_body residual
          int wb = gm / 49, nn = gm % 49;
          int b = wb >> 6, rem = wb & 63;
          int h = (rem >> 3) * 7 + nn / 7, w = (rem & 7) * 7 + nn % 7;
          size_t nat = (size_t)(b * 3136 + h * 56 + w);
          outf[nat * 256 + gn] = v + bias[gn] + resid[nat * 256 + gn];
        } else if constexpr (EPI == 3) {
          float x = v + bias[gn];
          outb[(size_t)gm * N + gn] =
              __float2bfloat16(0.5f * x * (1.0f + erff(x * 0.70710678118654752f)));
        } else {  // EPI == 4
          outf[(size_t)gm * N + gn] = v + bias[gn] + resid[(size_t)gm * 256 + gn];
        }
      }
    }
  }
}

// ---------------------------------------------------------------------------
// Windowed attention: one block per (window, head).  N=49, HD=32.
__global__ void k_attn(const __hip_bfloat16* __restrict__ qb,
                       const __hip_bfloat16* __restrict__ kvb,
                       const float* __restrict__ rpb,
                       __hip_bfloat16* __restrict__ ob) {
  int wb = blockIdx.x >> 3;
  int hd = blockIdx.x & 7;
  __shared__ float qs[49][32];
  __shared__ float ks[49][33];  // +1 pad: lanes stride rows in QK^T
  __shared__ float vs[49][32];
  __shared__ float ss[49][50];
  int tid = threadIdx.x;
  for (int idx = tid; idx < 49 * 32; idx += 256) {
    int n = idx >> 5, d = idx & 31;
    qs[n][d] = (float)qb[(size_t)(wb * 49 + n) * 256 + hd * 32 + d];
    ks[n][d] = (float)kvb[(size_t)(wb * 49 + n) * 512 + hd * 32 + d];
    vs[n][d] = (float)kvb[(size_t)(wb * 49 + n) * 512 + 256 + hd * 32 + d];
  }
  __syncthreads();
  for (int idx = tid; idx < 49 * 49; idx += 256) {
    int i = idx / 49, j = idx % 49;
    float s = 0.f;
#pragma unroll
    for (int k = 0; k < 32; ++k) s += qs[i][k] * ks[j][k];
    int yi = i / 7, xi = i % 7, yj = j / 7, xj = j % 7;
    int rel = (yi - yj + 6) * 13 + (xi - xj + 6);
    ss[i][j] = s + rpb[rel * 8 + hd];
  }
  __syncthreads();
  if (tid < 49) {
    float m = -1e30f;
    for (int j = 0; j < 49; ++j) m = fmaxf(m, ss[tid][j]);
    float sum = 0.f;
    for (int j = 0; j < 49; ++j) { float e = expf(ss[tid][j] - m); ss[tid][j] = e; sum += e; }
    float inv = 1.0f / sum;
    for (int j = 0; j < 49; ++j) ss[tid][j] *= inv;
  }
  __syncthreads();
  for (int idx = tid; idx < 49 * 32; idx += 256) {
    int i = idx >> 5, d = idx & 31;
    float o = 0.f;
#pragma unroll
    for (int j = 0; j < 49; ++j) o += ss[i][j] * vs[j][d];
    ob[(size_t)(wb * 49 + i) * 256 + hd * 32 + d] = __float2bfloat16(o);
  }
}

// ---------------------------------------------------------------------------
// (B,HW,256) fp32 -> (B,256,HW) fp32 via 32x32 LDS tiles.
__global__ void k_transpose(const float* __restrict__ y, float* __restrict__ out) {
  __shared__ float t[32][33];
  int bb = blockIdx.z;
  int hw0 = blockIdx.x * 32;
  int o0 = blockIdx.y * 32;
  int tx = threadIdx.x, ty = threadIdx.y;  // 32 x 8
#pragma unroll
  for (int r = 0; r < 4; ++r)
    t[ty + r * 8][tx] = y[(size_t)(bb * 3136 + hw0 + ty + r * 8) * 256 + o0 + tx];
  __syncthreads();
#pragma unroll
  for (int r = 0; r < 4; ++r)
    out[(size_t)(bb * 256 + o0 + ty + r * 8) * 3136 + hw0 + tx] = t[tx][ty + r * 8];
}

// ---------------------------------------------------------------------------
extern "C" void kernel_launch(void* const* d_in, const int* in_sizes, int n_in,
                              void* d_out, int out_size, void* d_ws, size_t ws_size,
                              hipStream_t stream) {
  const float* x_edge = (const float*)d_in[0];
  const float* x_body = (const float*)d_in[1];
  const float* ne_w   = (const float*)d_in[2];
  const float* ne_b   = (const float*)d_in[3];
  const float* conv_w = (const float*)d_in[4];
  const float* n1_w   = (const float*)d_in[5];
  const float* n1_b   = (const float*)d_in[6];
  const float* rpb    = (const float*)d_in[7];
  const float* q_w    = (const float*)d_in[8];
  const float* kv_w   = (const float*)d_in[9];
  const float* proj_w = (const float*)d_in[10];
  const float* proj_b = (const float*)d_in[11];
  const float* n2_w   = (const float*)d_in[12];
  const float* n2_b   = (const float*)d_in[13];
  const float* fc1_w  = (const float*)d_in[14];
  const float* fc1_b  = (const float*)d_in[15];
  const float* fc2_w  = (const float*)d_in[16];
  const float* fc2_b  = (const float*)d_in[17];
  float* out = (float*)d_out;
  (void)in_sizes; (void)n_in; (void)out_size; (void)ws_size;

  // ---- workspace layout (explicit, overlap-audited) ----
  // Sizes (bytes):
  const size_t SZ_Ae    = (size_t)M_ * 128 * 2;   //  12,845,056
  const size_t SZ_bf256 = (size_t)M_ * 256 * 2;   //  25,690,112
  const size_t SZ_bf512 = (size_t)M_ * 512 * 2;   //  51,380,224
  const size_t SZ_h1    = (size_t)M_ * 1024 * 2;  // 102,760,448
  const size_t SZ_f256  = (size_t)M_ * 256 * 4;   //  51,380,224

  char* ws = (char*)d_ws;
  float* stats = (float*)ws;                      // 256 B
  char*  P     = ws + 256;                        // pool base
  // Phase-1 pool members (all dead by the fc1 GEMM):
  __hip_bfloat16* Ae    = (__hip_bfloat16*)(P);
  __hip_bfloat16* xbn   = (__hip_bfloat16*)(P + SZ_Ae);
  __hip_bfloat16* xec   = (__hip_bfloat16*)(P + SZ_Ae + SZ_bf256);
  __hip_bfloat16* qb    = (__hip_bfloat16*)(P + SZ_Ae + 2 * SZ_bf256);
  __hip_bfloat16* kvb   = (__hip_bfloat16*)(P + SZ_Ae + 3 * SZ_bf256);
  __hip_bfloat16* attnb = (__hip_bfloat16*)(P + SZ_Ae + 3 * SZ_bf256 + SZ_bf512);
  // Reuse (lifetimes audited):
  //   h1 @ P+0 (fc1 out, 102.8MB): Ae..attnb all dead when fc1 runs.
  //   xn @ P+104MB (ln2 out): beyond h1 end; dead before fc2.
  //   yb @ P+104MB (fc2 out): written while fc2 reads h1 [P, P+102.8MB) - no overlap.
  //   xf -> d_out (51.4MB): residual spine; fully overwritten by final transpose.
  __hip_bfloat16* h1 = (__hip_bfloat16*)(P);
  char* tail         = P + ((SZ_h1 + 1024 * 1024) & ~(size_t)1023);  // ~103.8MB
  __hip_bfloat16* xn = (__hip_bfloat16*)tail;
  float*          yb = (float*)tail;
  float*          xf = (float*)d_out;
  // Total ws usage: 256 + max(pool end ~167MB, tail + 51.4MB ~155MB) ≈ 167 MB.

  const float qscale = 0.17677669529663687f;  // HD^-0.5

  k_stats<<<16, 256, 0, stream>>>(x_edge, stats);
  k_prep_edge<<<1024, 256, 0, stream>>>(x_edge, ne_w, ne_b, stats, Ae);
  k_ln_rows<true><<<M_ / 4, 256, 0, stream>>>(x_body, n1_w, n1_b, xbn);
  // conv: (M x 128) @ (256 x 128)^T -> xe_conv (windowed)
  gemm_bt<0><<<dim3(2, 392), 256, 0, stream>>>(Ae, conv_w, M_, 256, 128, xec, nullptr, nullptr, nullptr, 0.f);
  // q: xe_conv @ q_w^T, scaled
  gemm_bt<1><<<dim3(2, 392), 256, 0, stream>>>(xec, q_w, M_, 256, 256, qb, nullptr, nullptr, nullptr, qscale);
  // kv: xb_norm @ kv_w^T
  gemm_bt<0><<<dim3(4, 392), 256, 0, stream>>>(xbn, kv_w, M_, 512, 256, kvb, nullptr, nullptr, nullptr, 0.f);
  k_attn<<<8192, 256, 0, stream>>>(qb, kvb, rpb, attnb);
  // proj + bias + residual(x_body), windowed->natural rows, fp32 x -> d_out (xf)
  gemm_bt<2><<<dim3(2, 392), 256, 0, stream>>>(attnb, proj_w, M_, 256, 256, nullptr, xf, proj_b, x_body, 0.f);
  k_ln_rows<false><<<M_ / 4, 256, 0, stream>>>(xf, n2_w, n2_b, xn);
  // fc1 + bias + gelu
  gemm_bt<3><<<dim3(8, 392), 256, 0, stream>>>(xn, fc1_w, M_, 1024, 256, h1, nullptr, fc1_b, nullptr, 0.f);
  // fc2 + bias + residual(xf)
  gemm_bt<4><<<dim3(2, 392), 256, 0, stream>>>(h1, fc2_w, M_, 256, 1024, nullptr, yb, fc2_b, xf, 0.f);
  k_transpose<<<dim3(98, 8, 16), dim3(32, 8), 0, stream>>>(yb, out);
}

// Round 3
// 651.440 us; speedup vs baseline: 1.2384x; 1.2384x over previous
//
#include <hip/hip_runtime.h>
#include <hip/hip_bf16.h>
#include <math.h>

// Problem constants
#define B_    16
#define CE_   128
#define CB_   256
#define H_    56
#define W_    56
#define NH_   8
#define WS_   7
#define HD_   32
#define NWIN_ 49      // WS*WS
#define HW_   3136    // H*W
#define M_    50176   // B*H*W rows
#define HID_  1024

typedef short bf16x8 __attribute__((ext_vector_type(8)));
typedef float f32x4  __attribute__((ext_vector_type(4)));

__device__ __forceinline__ float waveRedSum(float v) {
#pragma unroll
  for (int off = 32; off; off >>= 1) v += __shfl_xor(v, off, 64);
  return v;
}

// Async global->LDS, 16B per lane.  LDS dest = wave-uniform base + lane*16.
__device__ __forceinline__ void load_lds16(const void* g, void* l) {
  __builtin_amdgcn_global_load_lds((__attribute__((address_space(1))) void*)g,
                                   (__attribute__((address_space(3))) void*)l,
                                   16, 0, 0);
}

// ---------------------------------------------------------------------------
// x_edge stats, stage 1: 1024 blocks (64 per batch), partial sums to ws.
__global__ void k_stats1(const float* __restrict__ xe, float* __restrict__ part) {
  int blk = blockIdx.x;
  int b = blk >> 6, s = blk & 63;
  const float4* p = (const float4*)(xe + (size_t)b * 401408 + s * 6272);
  float sm = 0.f, s2 = 0.f;
  for (int i = threadIdx.x; i < 1568; i += 256) {
    float4 v = p[i];
    sm += v.x + v.y + v.z + v.w;
    s2 += v.x * v.x + v.y * v.y + v.z * v.z + v.w * v.w;
  }
  sm = waveRedSum(sm); s2 = waveRedSum(s2);
  __shared__ float aux[8];
  int wave = threadIdx.x >> 6, lane = threadIdx.x & 63;
  if (lane == 0) { aux[wave] = sm; aux[4 + wave] = s2; }
  __syncthreads();
  if (threadIdx.x == 0) {
    part[blk * 2]     = aux[0] + aux[1] + aux[2] + aux[3];
    part[blk * 2 + 1] = aux[4] + aux[5] + aux[6] + aux[7];
  }
}

// stage 2: 16 blocks x 64 threads -> mean/rstd per batch.
__global__ void k_stats2(const float* __restrict__ part, float* __restrict__ stats) {
  int b = blockIdx.x, lane = threadIdx.x;
  float sm = part[(b * 64 + lane) * 2];
  float s2 = part[(b * 64 + lane) * 2 + 1];
  sm = waveRedSum(sm); s2 = waveRedSum(s2);
  if (lane == 0) {
    float mean = sm / 401408.0f;
    float var  = s2 / 401408.0f - mean * mean;
    stats[b * 2] = mean;
    stats[b * 2 + 1] = rsqrtf(var + 1e-5f);
  }
}

// ---------------------------------------------------------------------------
// Cast all 6 weight matrices fp32 -> bf16 into one contiguous buffer.
// Segments (elem offsets): conv@0(32768) q@32768(65536) kv@98304(131072)
// proj@229376(65536) fc1@294912(262144) fc2@557056(262144); total 819200.
__global__ void k_cast6(const float* __restrict__ s0, const float* __restrict__ s1,
                        const float* __restrict__ s2, const float* __restrict__ s3,
                        const float* __restrict__ s4, const float* __restrict__ s5,
                        __hip_bfloat16* __restrict__ d) {
  size_t i4 = ((size_t)blockIdx.x * 256 + threadIdx.x) * 4;
  if (i4 >= 819200) return;
  const float* src; size_t off;
  if      (i4 < 32768)  { src = s0; off = 0; }
  else if (i4 < 98304)  { src = s1; off = 32768; }
  else if (i4 < 229376) { src = s2; off = 98304; }
  else if (i4 < 294912) { src = s3; off = 229376; }
  else if (i4 < 557056) { src = s4; off = 294912; }
  else                  { src = s5; off = 557056; }
  float4 v = *(const float4*)(src + (i4 - off));
  union { __hip_bfloat16 h[4]; uint2 u; } pk;
  pk.h[0] = __float2bfloat16(v.x);
  pk.h[1] = __float2bfloat16(v.y);
  pk.h[2] = __float2bfloat16(v.z);
  pk.h[3] = __float2bfloat16(v.w);
  *(uint2*)(d + i4) = pk.u;
}

// ---------------------------------------------------------------------------
// Normalize x_edge (per-element affine), emit bf16 A matrix in WINDOWED row
// order: row m = wb*49 + p, cols = 128 channels.  1024 blocks (one/window).
__global__ void k_prep_edge(const float* __restrict__ xe,
                            const float* __restrict__ we,
                            const float* __restrict__ be,
                            const float* __restrict__ stats,
                            __hip_bfloat16* __restrict__ Ae) {
  int wb = blockIdx.x;
  int b = wb >> 6, rem = wb & 63;
  int h0 = (rem >> 3) * 7, w0 = (rem & 7) * 7;
  float mean = stats[b * 2], rstd = stats[b * 2 + 1];
  __shared__ __hip_bfloat16 t[49 * 130];  // [p][c], pad 130 to break bank stride
  for (int idx = threadIdx.x; idx < 128 * 49; idx += 256) {
    int c = idx / 49, p = idx % 49;
    int h = h0 + p / 7, w = w0 + p % 7;
    int off = (c * 56 + h) * 56 + w;
    float v = xe[(size_t)b * 401408 + off];
    t[p * 130 + c] = __float2bfloat16((v - mean) * rstd * we[off] + be[off]);
  }
  __syncthreads();
  __hip_bfloat16* dst = Ae + (size_t)wb * 49 * 128;
  for (int idx = threadIdx.x; idx < 49 * 128; idx += 256) {
    int p = idx >> 7, c = idx & 127;
    dst[idx] = t[p * 130 + c];
  }
}

// ---------------------------------------------------------------------------
// Row LayerNorm over 256 channels; one wave per row, 4 rows/block.
// PERM=true: write rows in windowed order (for x_body -> KV path).
template <bool PERM>
__global__ void k_ln_rows(const float* __restrict__ x,
                          const float* __restrict__ w,
                          const float* __restrict__ bia,
                          __hip_bfloat16* __restrict__ out) {
  int row = blockIdx.x * 4 + (threadIdx.x >> 6);
  int lane = threadIdx.x & 63;
  float4 xv = *(const float4*)(x + (size_t)row * 256 + lane * 4);
  float s  = xv.x + xv.y + xv.z + xv.w;
  float s2 = xv.x * xv.x + xv.y * xv.y + xv.z * xv.z + xv.w * xv.w;
  s = waveRedSum(s); s2 = waveRedSum(s2);
  float mean = s * (1.0f / 256.0f);
  float var  = s2 * (1.0f / 256.0f) - mean * mean;
  float rstd = rsqrtf(var + 1e-5f);
  int orow = row;
  if (PERM) {
    int b = row / 3136, hw = row % 3136;
    int h = hw / 56, ww = hw % 56;
    orow = (b * 64 + (h / 7) * 8 + (ww / 7)) * 49 + (h % 7) * 7 + (ww % 7);
  }
  float4 wv = *(const float4*)(w + lane * 4);
  float4 bv = *(const float4*)(bia + lane * 4);
  union { __hip_bfloat16 h[4]; uint2 u; } pk;
  pk.h[0] = __float2bfloat16((xv.x - mean) * rstd * wv.x + bv.x);
  pk.h[1] = __float2bfloat16((xv.y - mean) * rstd * wv.y + bv.y);
  pk.h[2] = __float2bfloat16((xv.z - mean) * rstd * wv.z + bv.z);
  pk.h[3] = __float2bfloat16((xv.w - mean) * rstd * wv.w + bv.w);
  *(uint2*)(out + (size_t)orow * 256 + lane * 4) = pk.u;
}

// ---------------------------------------------------------------------------
// MFMA GEMM:  C(MxN) = A(MxK,bf16) * W(NxK,bf16)^T   with epilogues.
// 128x128 tile, BK=32, 256 threads (4 waves, each 64x64 via 4x4 16x16 frags).
// Staging via global_load_lds width=16 (m97 pattern).  LDS layout [q][128][8]
// is lane-linear: wave w pass p covers q=(w>>1)+2p, rows (w&1)*64+lane.
// EPI: 0 store bf16 | 1 scale+bf16 | 2 proj(+bias+resid, permute rows, f32)
//      3 bias+gelu bf16 | 4 bias+resid f32
template <int EPI>
__launch_bounds__(256)
__global__ void gemm_bt(const __hip_bfloat16* __restrict__ A,
                        const __hip_bfloat16* __restrict__ Bw,
                        int M, int N, int K,
                        __hip_bfloat16* __restrict__ outb,
                        float* __restrict__ outf,
                        const float* __restrict__ bias,
                        const float* __restrict__ resid,
                        float scale) {
  __shared__ __hip_bfloat16 As[4 * 128 * 8];  // 8 KB
  __shared__ __hip_bfloat16 Bs[4 * 128 * 8];  // 8 KB
  const int tid  = threadIdx.x;
  const int lane = tid & 63;
  const int wave = tid >> 6;
  const int quad = lane >> 4;
  const int lm   = lane & 15;
  const int wm   = (wave & 1) << 6;
  const int wn   = (wave >> 1) << 6;
  const int n0   = blockIdx.x * 128;
  const int m0   = blockIdx.y * 128;

  // staging coords for this wave
  const int rh = (wave & 1) * 64;   // row-half base
  const int qw = wave >> 1;         // base k-quad
  const __hip_bfloat16* Arow = A  + (size_t)(m0 + rh + lane) * K;
  const __hip_bfloat16* Brow = Bw + (size_t)(n0 + rh + lane) * K;

  f32x4 acc[4][4];
#pragma unroll
  for (int i = 0; i < 4; ++i)
#pragma unroll
    for (int j = 0; j < 4; ++j)
#pragma unroll
      for (int r = 0; r < 4; ++r) acc[i][j][r] = 0.f;

  for (int k0 = 0; k0 < K; k0 += 32) {
#pragma unroll
    for (int p = 0; p < 2; ++p) {
      int q = qw + 2 * p;
      load_lds16(Arow + k0 + q * 8, &As[(q * 128 + rh) * 8]);
      load_lds16(Brow + k0 + q * 8, &Bs[(q * 128 + rh) * 8]);
    }
    __syncthreads();
    bf16x8 af[4], bfr[4];
#pragma unroll
    for (int i = 0; i < 4; ++i)
      af[i] = *(const bf16x8*)&As[(quad * 128 + wm + i * 16 + lm) * 8];
#pragma unroll
    for (int j = 0; j < 4; ++j)
      bfr[j] = *(const bf16x8*)&Bs[(quad * 128 + wn + j * 16 + lm) * 8];
#pragma unroll
    for (int i = 0; i < 4; ++i)
#pragma unroll
      for (int j = 0; j < 4; ++j)
        acc[i][j] = __builtin_amdgcn_mfma_f32_16x16x32_bf16(af[i], bfr[j], acc[i][j], 0, 0, 0);
    __syncthreads();
  }

#pragma unroll
  for (int i = 0; i < 4; ++i) {
#pragma unroll
    for (int j = 0; j < 4; ++j) {
#pragma unroll
      for (int r = 0; r < 4; ++r) {
        int gm = m0 + wm + i * 16 + quad * 4 + r;
        int gn = n0 + wn + j * 16 + lm;
        float v = acc[i][j][r];
        if constexpr (EPI == 0) {
          outb[(size_t)gm * N + gn] = __float2bfloat16(v);
        } else if constexpr (EPI == 1) {
          outb[(size_t)gm * N + gn] = __float2bfloat16(v * scale);
        } else if constexpr (EPI == 2) {
          // windowed row -> natural row, add proj bias + x_body residual
          int wb = gm / 49, nn = gm % 49;
          int b = wb >> 6, rem = wb & 63;
          int h = (rem >> 3) * 7 + nn / 7, w = (rem & 7) * 7 + nn % 7;
          size_t nat = (size_t)(b * 3136 + h * 56 + w);
          outf[nat * 256 + gn] = v + bias[gn] + resid[nat * 256 + gn];
        } else if constexpr (EPI == 3) {
          float x = v + bias[gn];
          outb[(size_t)gm * N + gn] =
              __float2bfloat16(0.5f * x * (1.0f + erff(x * 0.70710678118654752f)));
        } else {  // EPI == 4
          outf[(size_t)gm * N + gn] = v + bias[gn] + resid[(size_t)gm * 256 + gn];
        }
      }
    }
  }
}

// ---------------------------------------------------------------------------
// Windowed attention: one block per (window, head).  N=49, HD=32.
__global__ void k_attn(const __hip_bfloat16* __restrict__ qb,
                       const __hip_bfloat16* __restrict__ kvb,
                       const float* __restrict__ rpb,
                       __hip_bfloat16* __restrict__ ob) {
  int wb = blockIdx.x >> 3;
  int hd = blockIdx.x & 7;
  __shared__ float qs[49][32];
  __shared__ float ks[49][33];  // +1 pad: lanes stride rows in QK^T
  __shared__ float vs[49][32];
  __shared__ float ss[49][50];
  int tid = threadIdx.x;
  for (int idx = tid; idx < 49 * 32; idx += 256) {
    int n = idx >> 5, d = idx & 31;
    qs[n][d] = (float)qb[(size_t)(wb * 49 + n) * 256 + hd * 32 + d];
    ks[n][d] = (float)kvb[(size_t)(wb * 49 + n) * 512 + hd * 32 + d];
    vs[n][d] = (float)kvb[(size_t)(wb * 49 + n) * 512 + 256 + hd * 32 + d];
  }
  __syncthreads();
  for (int idx = tid; idx < 49 * 49; idx += 256) {
    int i = idx / 49, j = idx % 49;
    float s = 0.f;
#pragma unroll
    for (int k = 0; k < 32; ++k) s += qs[i][k] * ks[j][k];
    int yi = i / 7, xi = i % 7, yj = j / 7, xj = j % 7;
    int rel = (yi - yj + 6) * 13 + (xi - xj + 6);
    ss[i][j] = s + rpb[rel * 8 + hd];
  }
  __syncthreads();
  if (tid < 49) {
    float m = -1e30f;
    for (int j = 0; j < 49; ++j) m = fmaxf(m, ss[tid][j]);
    float sum = 0.f;
    for (int j = 0; j < 49; ++j) { float e = expf(ss[tid][j] - m); ss[tid][j] = e; sum += e; }
    float inv = 1.0f / sum;
    for (int j = 0; j < 49; ++j) ss[tid][j] *= inv;
  }
  __syncthreads();
  for (int idx = tid; idx < 49 * 32; idx += 256) {
    int i = idx >> 5, d = idx & 31;
    float o = 0.f;
#pragma unroll
    for (int j = 0; j < 49; ++j) o += ss[i][j] * vs[j][d];
    ob[(size_t)(wb * 49 + i) * 256 + hd * 32 + d] = __float2bfloat16(o);
  }
}

// ---------------------------------------------------------------------------
// (B,HW,256) fp32 -> (B,256,HW) fp32 via 32x32 LDS tiles.
__global__ void k_transpose(const float* __restrict__ y, float* __restrict__ out) {
  __shared__ float t[32][33];
  int bb = blockIdx.z;
  int hw0 = blockIdx.x * 32;
  int o0 = blockIdx.y * 32;
  int tx = threadIdx.x, ty = threadIdx.y;  // 32 x 8
#pragma unroll
  for (int r = 0; r < 4; ++r)
    t[ty + r * 8][tx] = y[(size_t)(bb * 3136 + hw0 + ty + r * 8) * 256 + o0 + tx];
  __syncthreads();
#pragma unroll
  for (int r = 0; r < 4; ++r)
    out[(size_t)(bb * 256 + o0 + ty + r * 8) * 3136 + hw0 + tx] = t[tx][ty + r * 8];
}

// ---------------------------------------------------------------------------
extern "C" void kernel_launch(void* const* d_in, const int* in_sizes, int n_in,
                              void* d_out, int out_size, void* d_ws, size_t ws_size,
                              hipStream_t stream) {
  const float* x_edge = (const float*)d_in[0];
  const float* x_body = (const float*)d_in[1];
  const float* ne_w   = (const float*)d_in[2];
  const float* ne_b   = (const float*)d_in[3];
  const float* conv_w = (const float*)d_in[4];
  const float* n1_w   = (const float*)d_in[5];
  const float* n1_b   = (const float*)d_in[6];
  const float* rpb    = (const float*)d_in[7];
  const float* q_w    = (const float*)d_in[8];
  const float* kv_w   = (const float*)d_in[9];
  const float* proj_w = (const float*)d_in[10];
  const float* proj_b = (const float*)d_in[11];
  const float* n2_w   = (const float*)d_in[12];
  const float* n2_b   = (const float*)d_in[13];
  const float* fc1_w  = (const float*)d_in[14];
  const float* fc1_b  = (const float*)d_in[15];
  const float* fc2_w  = (const float*)d_in[16];
  const float* fc2_b  = (const float*)d_in[17];
  float* out = (float*)d_out;
  (void)in_sizes; (void)n_in; (void)out_size; (void)ws_size;

  // ---- workspace layout (explicit, overlap-audited) ----
  const size_t SZ_Ae    = (size_t)M_ * 128 * 2;   //  12,845,056
  const size_t SZ_bf256 = (size_t)M_ * 256 * 2;   //  25,690,112
  const size_t SZ_bf512 = (size_t)M_ * 512 * 2;   //  51,380,224
  const size_t SZ_h1    = (size_t)M_ * 1024 * 2;  // 102,760,448

  char* ws = (char*)d_ws;
  __hip_bfloat16* Wb = (__hip_bfloat16*)ws;       // 819200 bf16 = 1,638,400 B (persists)
  float* part  = (float*)(ws + 1638400);          // 1024*2 f32 = 8 KB
  float* stats = (float*)(ws + 1638400 + 8192);   // 32 f32
  char*  P     = ws + 1638400 + 8192 + 256;       // pool base
  // bf16 weight segment pointers
  __hip_bfloat16* w_conv = Wb;
  __hip_bfloat16* w_q    = Wb + 32768;
  __hip_bfloat16* w_kv   = Wb + 98304;
  __hip_bfloat16* w_proj = Wb + 229376;
  __hip_bfloat16* w_fc1  = Wb + 294912;
  __hip_bfloat16* w_fc2  = Wb + 557056;
  // Phase-1 pool members (all dead by the fc1 GEMM):
  __hip_bfloat16* Ae    = (__hip_bfloat16*)(P);
  __hip_bfloat16* xbn   = (__hip_bfloat16*)(P + SZ_Ae);
  __hip_bfloat16* xec   = (__hip_bfloat16*)(P + SZ_Ae + SZ_bf256);
  __hip_bfloat16* qb    = (__hip_bfloat16*)(P + SZ_Ae + 2 * SZ_bf256);
  __hip_bfloat16* kvb   = (__hip_bfloat16*)(P + SZ_Ae + 3 * SZ_bf256);
  __hip_bfloat16* attnb = (__hip_bfloat16*)(P + SZ_Ae + 3 * SZ_bf256 + SZ_bf512);
  // Reuse (lifetimes audited):
  //   h1 @ P+0 (fc1 out, 102.8MB): Ae..attnb all dead when fc1 runs.
  //   xn @ P+104MB (ln2 out): beyond h1 end; dead before fc2.
  //   yb @ P+104MB (fc2 out): written while fc2 reads h1 [P, P+102.8MB) - no overlap.
  //   xf -> d_out (51.4MB): residual spine; fully overwritten by final transpose.
  __hip_bfloat16* h1 = (__hip_bfloat16*)(P);
  char* tail         = P + ((SZ_h1 + 1024 * 1024) & ~(size_t)1023);  // ~103.8MB
  __hip_bfloat16* xn = (__hip_bfloat16*)tail;
  float*          yb = (float*)tail;
  float*          xf = (float*)d_out;

  const float qscale = 0.17677669529663687f;  // HD^-0.5

  k_cast6<<<800, 256, 0, stream>>>(conv_w, q_w, kv_w, proj_w, fc1_w, fc2_w, Wb);
  k_stats1<<<1024, 256, 0, stream>>>(x_edge, part);
  k_stats2<<<16, 64, 0, stream>>>(part, stats);
  k_prep_edge<<<1024, 256, 0, stream>>>(x_edge, ne_w, ne_b, stats, Ae);
  k_ln_rows<true><<<M_ / 4, 256, 0, stream>>>(x_body, n1_w, n1_b, xbn);
  // conv: (M x 128) @ (256 x 128)^T -> xe_conv (windowed)
  gemm_bt<0><<<dim3(2, 392), 256, 0, stream>>>(Ae, w_conv, M_, 256, 128, xec, nullptr, nullptr, nullptr, 0.f);
  // q: xe_conv @ q_w^T, scaled
  gemm_bt<1><<<dim3(2, 392), 256, 0, stream>>>(xec, w_q, M_, 256, 256, qb, nullptr, nullptr, nullptr, qscale);
  // kv: xb_norm @ kv_w^T
  gemm_bt<0><<<dim3(4, 392), 256, 0, stream>>>(xbn, w_kv, M_, 512, 256, kvb, nullptr, nullptr, nullptr, 0.f);
  k_attn<<<8192, 256, 0, stream>>>(qb, kvb, rpb, attnb);
  // proj + bias + residual(x_body), windowed->natural rows, fp32 x -> d_out (xf)
  gemm_bt<2><<<dim3(2, 392), 256, 0, stream>>>(attnb, w_proj, M_, 256, 256, nullptr, xf, proj_b, x_body, 0.f);
  k_ln_rows<false><<<M_ / 4, 256, 0, stream>>>(xf, n2_w, n2_b, xn);
  // fc1 + bias + gelu
  gemm_bt<3><<<dim3(8, 392), 256, 0, stream>>>(xn, w_fc1, M_, 1024, 256, h1, nullptr, fc1_b, nullptr, 0.f);
  // fc2 + bias + residual(xf)
  gemm_bt<4><<<dim3(2, 392), 256, 0, stream>>>(h1, w_fc2, M_, 256, 1024, nullptr, yb, fc2_b, xf, 0.f);
  k_transpose<<<dim3(98, 8, 16), dim3(32, 8), 0, stream>>>(yb, out);
}

// Round 4
// 561.901 us; speedup vs baseline: 1.4357x; 1.1594x over previous
//
#include <hip/hip_runtime.h>
#include <hip/hip_bf16.h>
#include <math.h>

// Problem constants
#define B_    16
#define CE_   128
#define CB_   256
#define H_    56
#define W_    56
#define NH_   8
#define WS_   7
#define HD_   32
#define NWIN_ 49      // WS*WS
#define HW_   3136    // H*W
#define M_    50176   // B*H*W rows
#define HID_  1024

typedef short bf16x8 __attribute__((ext_vector_type(8)));
typedef float f32x4  __attribute__((ext_vector_type(4)));

__device__ __forceinline__ float waveRedSum(float v) {
#pragma unroll
  for (int off = 32; off; off >>= 1) v += __shfl_xor(v, off, 64);
  return v;
}

// Async global->LDS, 16B per lane.  LDS dest = wave-uniform base + lane*16.
__device__ __forceinline__ void load_lds16(const void* g, void* l) {
  __builtin_amdgcn_global_load_lds((__attribute__((address_space(1))) void*)g,
                                   (__attribute__((address_space(3))) void*)l,
                                   16, 0, 0);
}

// ---------------------------------------------------------------------------
// x_edge stats, stage 1: 1024 blocks (64 per batch), partial sums to ws.
__global__ void k_stats1(const float* __restrict__ xe, float* __restrict__ part) {
  int blk = blockIdx.x;
  int b = blk >> 6, s = blk & 63;
  const float4* p = (const float4*)(xe + (size_t)b * 401408 + s * 6272);
  float sm = 0.f, s2 = 0.f;
  for (int i = threadIdx.x; i < 1568; i += 256) {
    float4 v = p[i];
    sm += v.x + v.y + v.z + v.w;
    s2 += v.x * v.x + v.y * v.y + v.z * v.z + v.w * v.w;
  }
  sm = waveRedSum(sm); s2 = waveRedSum(s2);
  __shared__ float aux[8];
  int wave = threadIdx.x >> 6, lane = threadIdx.x & 63;
  if (lane == 0) { aux[wave] = sm; aux[4 + wave] = s2; }
  __syncthreads();
  if (threadIdx.x == 0) {
    part[blk * 2]     = aux[0] + aux[1] + aux[2] + aux[3];
    part[blk * 2 + 1] = aux[4] + aux[5] + aux[6] + aux[7];
  }
}

// stage 2: 16 blocks x 64 threads -> mean/rstd per batch.
__global__ void k_stats2(const float* __restrict__ part, float* __restrict__ stats) {
  int b = blockIdx.x, lane = threadIdx.x;
  float sm = part[(b * 64 + lane) * 2];
  float s2 = part[(b * 64 + lane) * 2 + 1];
  sm = waveRedSum(sm); s2 = waveRedSum(s2);
  if (lane == 0) {
    float mean = sm / 401408.0f;
    float var  = s2 / 401408.0f - mean * mean;
    stats[b * 2] = mean;
    stats[b * 2 + 1] = rsqrtf(var + 1e-5f);
  }
}

// ---------------------------------------------------------------------------
// Cast all 6 weight matrices fp32 -> bf16 into one contiguous buffer.
__global__ void k_cast6(const float* __restrict__ s0, const float* __restrict__ s1,
                        const float* __restrict__ s2, const float* __restrict__ s3,
                        const float* __restrict__ s4, const float* __restrict__ s5,
                        __hip_bfloat16* __restrict__ d) {
  size_t i4 = ((size_t)blockIdx.x * 256 + threadIdx.x) * 4;
  if (i4 >= 819200) return;
  const float* src; size_t off;
  if      (i4 < 32768)  { src = s0; off = 0; }
  else if (i4 < 98304)  { src = s1; off = 32768; }
  else if (i4 < 229376) { src = s2; off = 98304; }
  else if (i4 < 294912) { src = s3; off = 229376; }
  else if (i4 < 557056) { src = s4; off = 294912; }
  else                  { src = s5; off = 557056; }
  float4 v = *(const float4*)(src + (i4 - off));
  union { __hip_bfloat16 h[4]; uint2 u; } pk;
  pk.h[0] = __float2bfloat16(v.x);
  pk.h[1] = __float2bfloat16(v.y);
  pk.h[2] = __float2bfloat16(v.z);
  pk.h[3] = __float2bfloat16(v.w);
  *(uint2*)(d + i4) = pk.u;
}

// ---------------------------------------------------------------------------
// Precompute rel-pos bias in MFMA C-fragment order + padding mask.
// Layout: bp[(((h*4+ti)*4+tj)*64 + lane)*4 + r], row=16ti+quad*4+r, col=16tj+lm.
// Padded rows/cols (>=49) get -1e30 (softmax mask).  128 blocks x 64 threads.
__global__ void k_bias_pre(const float* __restrict__ rpb, float* __restrict__ bp) {
  int blk = blockIdx.x;         // h*16 + ti*4 + tj
  int h = blk >> 4, tile = blk & 15;
  int ti = tile >> 2, tj = tile & 3;
  int lane = threadIdx.x;
  int quad = lane >> 4, lm = lane & 15;
  float4 v;
  float* vp = (float*)&v;
#pragma unroll
  for (int r = 0; r < 4; ++r) {
    int i = ti * 16 + quad * 4 + r;
    int j = tj * 16 + lm;
    float b = -1e30f;
    if (i < 49 && j < 49) {
      int rel = (i / 7 - j / 7 + 6) * 13 + (i % 7 - j % 7 + 6);
      b = rpb[rel * 8 + h];
    }
    vp[r] = b;
  }
  *(float4*)&bp[(size_t)(blk * 64 + lane) * 4] = v;
}

// ---------------------------------------------------------------------------
// Normalize x_edge (per-element affine), emit bf16 A matrix in WINDOWED row
// order: row m = wb*49 + p, cols = 128 channels.  1024 blocks (one/window).
__global__ void k_prep_edge(const float* __restrict__ xe,
                            const float* __restrict__ we,
                            const float* __restrict__ be,
                            const float* __restrict__ stats,
                            __hip_bfloat16* __restrict__ Ae) {
  int wb = blockIdx.x;
  int b = wb >> 6, rem = wb & 63;
  int h0 = (rem >> 3) * 7, w0 = (rem & 7) * 7;
  float mean = stats[b * 2], rstd = stats[b * 2 + 1];
  __shared__ __hip_bfloat16 t[49 * 130];  // [p][c], pad 130 to break bank stride
  for (int idx = threadIdx.x; idx < 128 * 49; idx += 256) {
    int c = idx / 49, p = idx % 49;
    int h = h0 + p / 7, w = w0 + p % 7;
    int off = (c * 56 + h) * 56 + w;
    float v = xe[(size_t)b * 401408 + off];
    t[p * 130 + c] = __float2bfloat16((v - mean) * rstd * we[off] + be[off]);
  }
  __syncthreads();
  __hip_bfloat16* dst = Ae + (size_t)wb * 49 * 128;
  for (int idx = threadIdx.x; idx < 49 * 128; idx += 256) {
    int p = idx >> 7, c = idx & 127;
    dst[idx] = t[p * 130 + c];
  }
}

// ---------------------------------------------------------------------------
// Row LayerNorm over 256 channels; one wave per row, 4 rows/block.
// PERM=true: write rows in windowed order (for x_body -> KV path).
template <bool PERM>
__global__ void k_ln_rows(const float* __restrict__ x,
                          const float* __restrict__ w,
                          const float* __restrict__ bia,
                          __hip_bfloat16* __restrict__ out) {
  int row = blockIdx.x * 4 + (threadIdx.x >> 6);
  int lane = threadIdx.x & 63;
  float4 xv = *(const float4*)(x + (size_t)row * 256 + lane * 4);
  float s  = xv.x + xv.y + xv.z + xv.w;
  float s2 = xv.x * xv.x + xv.y * xv.y + xv.z * xv.z + xv.w * xv.w;
  s = waveRedSum(s); s2 = waveRedSum(s2);
  float mean = s * (1.0f / 256.0f);
  float var  = s2 * (1.0f / 256.0f) - mean * mean;
  float rstd = rsqrtf(var + 1e-5f);
  int orow = row;
  if (PERM) {
    int b = row / 3136, hw = row % 3136;
    int h = hw / 56, ww = hw % 56;
    orow = (b * 64 + (h / 7) * 8 + (ww / 7)) * 49 + (h % 7) * 7 + (ww % 7);
  }
  float4 wv = *(const float4*)(w + lane * 4);
  float4 bv = *(const float4*)(bia + lane * 4);
  union { __hip_bfloat16 h[4]; uint2 u; } pk;
  pk.h[0] = __float2bfloat16((xv.x - mean) * rstd * wv.x + bv.x);
  pk.h[1] = __float2bfloat16((xv.y - mean) * rstd * wv.y + bv.y);
  pk.h[2] = __float2bfloat16((xv.z - mean) * rstd * wv.z + bv.z);
  pk.h[3] = __float2bfloat16((xv.w - mean) * rstd * wv.w + bv.w);
  *(uint2*)(out + (size_t)orow * 256 + lane * 4) = pk.u;
}

// ---------------------------------------------------------------------------
// MFMA GEMM:  C(MxN) = A(MxK,bf16) * W(NxK,bf16)^T   with epilogues.
// 128x128 tile, BK=32, 256 threads (4 waves, each 64x64 via 4x4 16x16 frags).
// EPI: 0 store bf16 | 1 scale+bf16 | 2 proj(+bias+resid, permute rows, f32)
//      3 bias+gelu bf16 | 4 bias+resid f32
template <int EPI>
__launch_bounds__(256)
__global__ void gemm_bt(const __hip_bfloat16* __restrict__ A,
                        const __hip_bfloat16* __restrict__ Bw,
                        int M, int N, int K,
                        __hip_bfloat16* __restrict__ outb,
                        float* __restrict__ outf,
                        const float* __restrict__ bias,
                        const float* __restrict__ resid,
                        float scale) {
  __shared__ __hip_bfloat16 As[4 * 128 * 8];  // 8 KB
  __shared__ __hip_bfloat16 Bs[4 * 128 * 8];  // 8 KB
  const int tid  = threadIdx.x;
  const int lane = tid & 63;
  const int wave = tid >> 6;
  const int quad = lane >> 4;
  const int lm   = lane & 15;
  const int wm   = (wave & 1) << 6;
  const int wn   = (wave >> 1) << 6;
  const int n0   = blockIdx.x * 128;
  const int m0   = blockIdx.y * 128;

  const int rh = (wave & 1) * 64;   // row-half base
  const int qw = wave >> 1;         // base k-quad
  const __hip_bfloat16* Arow = A  + (size_t)(m0 + rh + lane) * K;
  const __hip_bfloat16* Brow = Bw + (size_t)(n0 + rh + lane) * K;

  f32x4 acc[4][4];
#pragma unroll
  for (int i = 0; i < 4; ++i)
#pragma unroll
    for (int j = 0; j < 4; ++j)
#pragma unroll
      for (int r = 0; r < 4; ++r) acc[i][j][r] = 0.f;

  for (int k0 = 0; k0 < K; k0 += 32) {
#pragma unroll
    for (int p = 0; p < 2; ++p) {
      int q = qw + 2 * p;
      load_lds16(Arow + k0 + q * 8, &As[(q * 128 + rh) * 8]);
      load_lds16(Brow + k0 + q * 8, &Bs[(q * 128 + rh) * 8]);
    }
    __syncthreads();
    bf16x8 af[4], bfr[4];
#pragma unroll
    for (int i = 0; i < 4; ++i)
      af[i] = *(const bf16x8*)&As[(quad * 128 + wm + i * 16 + lm) * 8];
#pragma unroll
    for (int j = 0; j < 4; ++j)
      bfr[j] = *(const bf16x8*)&Bs[(quad * 128 + wn + j * 16 + lm) * 8];
#pragma unroll
    for (int i = 0; i < 4; ++i)
#pragma unroll
      for (int j = 0; j < 4; ++j)
        acc[i][j] = __builtin_amdgcn_mfma_f32_16x16x32_bf16(af[i], bfr[j], acc[i][j], 0, 0, 0);
    __syncthreads();
  }

#pragma unroll
  for (int i = 0; i < 4; ++i) {
#pragma unroll
    for (int j = 0; j < 4; ++j) {
#pragma unroll
      for (int r = 0; r < 4; ++r) {
        int gm = m0 + wm + i * 16 + quad * 4 + r;
        int gn = n0 + wn + j * 16 + lm;
        float v = acc[i][j][r];
        if constexpr (EPI == 0) {
          outb[(size_t)gm * N + gn] = __float2bfloat16(v);
        } else if constexpr (EPI == 1) {
          outb[(size_t)gm * N + gn] = __float2bfloat16(v * scale);
        } else if constexpr (EPI == 2) {
          int wb = gm / 49, nn = gm % 49;
          int b = wb >> 6, rem = wb & 63;
          int h = (rem >> 3) * 7 + nn / 7, w = (rem & 7) * 7 + nn % 7;
          size_t nat = (size_t)(b * 3136 + h * 56 + w);
          outf[nat * 256 + gn] = v + bias[gn] + resid[nat * 256 + gn];
        } else if constexpr (EPI == 3) {
          float x = v + bias[gn];
          outb[(size_t)gm * N + gn] =
              __float2bfloat16(0.5f * x * (1.0f + erff(x * 0.70710678118654752f)));
        } else {  // EPI == 4
          outf[(size_t)gm * N + gn] = v + bias[gn] + resid[(size_t)gm * 256 + gn];
        }
      }
    }
  }
}

// ---------------------------------------------------------------------------
// MFMA windowed attention: one WAVE per (window, head).  8192 blocks x 64 thr.
// Tokens padded 49->64.  QK^T: 16 mfma_16x16x32_bf16; bias from bp (fragment
// order, -1e30 masks pads); reg softmax (16-lane shuffles); P -> LDS (overlays
// dead Q/K); PV: 16 mfma vs LDS-transposed V.  Row norm folded into epilogue.
__launch_bounds__(64)
__global__ void k_attn_mfma(const __hip_bfloat16* __restrict__ qb,
                            const __hip_bfloat16* __restrict__ kvb,
                            const float* __restrict__ bp,
                            __hip_bfloat16* __restrict__ ob) {
  int wb = blockIdx.x >> 3;
  int h  = blockIdx.x & 7;
  // elems: Qs[64][40]=2560 | Ks[64][40]=2560 | Vt[32][72]=2304; Ps[64][72]=4608
  // overlays Qs+Ks (dead after QK frag loads).  Total 14848 B.
  __shared__ __align__(16) __hip_bfloat16 lds[7424];
  __hip_bfloat16* Qs = lds;
  __hip_bfloat16* Ks = lds + 2560;
  __hip_bfloat16* Vt = lds + 5120;
  __hip_bfloat16* Ps = lds;
  const int lane = threadIdx.x;
  const int quad = lane >> 4, lm = lane & 15;

  // zero pad rows 49..63 of Qs/Ks (cols 0..31 read by frags), all of Vt
  const __hip_bfloat16 zb = __float2bfloat16(0.f);
  for (int i = lane; i < 600; i += 64) { Qs[1960 + i] = zb; Ks[1960 + i] = zb; }
  {
    uint4 z; z.x = z.y = z.z = z.w = 0u;
    for (int i = lane; i < 288; i += 64) ((uint4*)Vt)[i] = z;
  }
  // stage Q, K, V(transposed).  lane = t*4+p over 16 tokens/pass.
  {
    int t = lane >> 2, p = lane & 3;
#pragma unroll
    for (int pass = 0; pass < 4; ++pass, t += 16) {
      if (t < 49) {
        size_t rq = (size_t)(wb * 49 + t);
        uint4 qv = *(const uint4*)(qb + rq * 256 + h * 32 + p * 8);
        *(uint4*)&Qs[t * 40 + p * 8] = qv;
        uint4 kv = *(const uint4*)(kvb + rq * 512 + h * 32 + p * 8);
        *(uint4*)&Ks[t * 40 + p * 8] = kv;
        union { uint4 u; __hip_bfloat16 e[8]; } vv;
        vv.u = *(const uint4*)(kvb + rq * 512 + 256 + h * 32 + p * 8);
#pragma unroll
        for (int i = 0; i < 8; ++i) Vt[(p * 8 + i) * 72 + t] = vv.e[i];
      }
    }
  }
  __builtin_amdgcn_s_waitcnt(0);

  // QK^T
  bf16x8 qf[4], kf[4];
#pragma unroll
  for (int i = 0; i < 4; ++i) qf[i] = *(const bf16x8*)&Qs[(i * 16 + lm) * 40 + quad * 8];
#pragma unroll
  for (int j = 0; j < 4; ++j) kf[j] = *(const bf16x8*)&Ks[(j * 16 + lm) * 40 + quad * 8];
  f32x4 s[4][4];
#pragma unroll
  for (int i = 0; i < 4; ++i)
#pragma unroll
    for (int j = 0; j < 4; ++j) {
      f32x4 z4; z4[0] = z4[1] = z4[2] = z4[3] = 0.f;
      s[i][j] = __builtin_amdgcn_mfma_f32_16x16x32_bf16(qf[i], kf[j], z4, 0, 0, 0);
    }
  // bias (+mask) in fragment order
#pragma unroll
  for (int ti = 0; ti < 4; ++ti)
#pragma unroll
    for (int tj = 0; tj < 4; ++tj) {
      f32x4 b = *(const f32x4*)&bp[(size_t)(((h * 4 + ti) * 4 + tj) * 64 + lane) * 4];
      s[ti][tj] += b;
    }
  // softmax over cols (rows live in 16-lane groups: row = 16ti + quad*4 + r)
  float mrow[4][4], srow[4][4];
#pragma unroll
  for (int ti = 0; ti < 4; ++ti)
#pragma unroll
    for (int r = 0; r < 4; ++r)
      mrow[ti][r] = fmaxf(fmaxf(s[ti][0][r], s[ti][1][r]), fmaxf(s[ti][2][r], s[ti][3][r]));
#pragma unroll
  for (int mask = 1; mask <= 8; mask <<= 1)
#pragma unroll
    for (int ti = 0; ti < 4; ++ti)
#pragma unroll
      for (int r = 0; r < 4; ++r)
        mrow[ti][r] = fmaxf(mrow[ti][r], __shfl_xor(mrow[ti][r], mask, 64));
#pragma unroll
  for (int ti = 0; ti < 4; ++ti)
#pragma unroll
    for (int tj = 0; tj < 4; ++tj)
#pragma unroll
      for (int r = 0; r < 4; ++r)
        s[ti][tj][r] = __expf(s[ti][tj][r] - mrow[ti][r]);
#pragma unroll
  for (int ti = 0; ti < 4; ++ti)
#pragma unroll
    for (int r = 0; r < 4; ++r)
      srow[ti][r] = s[ti][0][r] + s[ti][1][r] + s[ti][2][r] + s[ti][3][r];
#pragma unroll
  for (int mask = 1; mask <= 8; mask <<= 1)
#pragma unroll
    for (int ti = 0; ti < 4; ++ti)
#pragma unroll
      for (int r = 0; r < 4; ++r)
        srow[ti][r] += __shfl_xor(srow[ti][r], mask, 64);
  float inv[4][4];
#pragma unroll
  for (int ti = 0; ti < 4; ++ti)
#pragma unroll
    for (int r = 0; r < 4; ++r)
      inv[ti][r] = 1.0f / srow[ti][r];

  // P (unnormalized exp) C-layout -> LDS A-layout (overlay Q/K region)
#pragma unroll
  for (int ti = 0; ti < 4; ++ti)
#pragma unroll
    for (int tj = 0; tj < 4; ++tj)
#pragma unroll
      for (int r = 0; r < 4; ++r)
        Ps[(ti * 16 + quad * 4 + r) * 72 + tj * 16 + lm] = __float2bfloat16(s[ti][tj][r]);
  __builtin_amdgcn_s_waitcnt(0);

  // PV:  O(64x32) = P(64x64) * V(64x32),  B-frags from Vt rows (= V cols)
  f32x4 o[4][2];
#pragma unroll
  for (int mt = 0; mt < 4; ++mt)
#pragma unroll
    for (int nt = 0; nt < 2; ++nt)
#pragma unroll
      for (int r = 0; r < 4; ++r) o[mt][nt][r] = 0.f;
#pragma unroll
  for (int kq = 0; kq < 2; ++kq) {
    bf16x8 pa[4], vb[2];
#pragma unroll
    for (int mt = 0; mt < 4; ++mt)
      pa[mt] = *(const bf16x8*)&Ps[(mt * 16 + lm) * 72 + kq * 32 + quad * 8];
#pragma unroll
    for (int nt = 0; nt < 2; ++nt)
      vb[nt] = *(const bf16x8*)&Vt[(nt * 16 + lm) * 72 + kq * 32 + quad * 8];
#pragma unroll
    for (int mt = 0; mt < 4; ++mt)
#pragma unroll
      for (int nt = 0; nt < 2; ++nt)
        o[mt][nt] = __builtin_amdgcn_mfma_f32_16x16x32_bf16(pa[mt], vb[nt], o[mt][nt], 0, 0, 0);
  }
  // epilogue: normalize rows, store valid tokens
#pragma unroll
  for (int mt = 0; mt < 4; ++mt)
#pragma unroll
    for (int r = 0; r < 4; ++r) {
      int row = mt * 16 + quad * 4 + r;
      if (row < 49) {
#pragma unroll
        for (int nt = 0; nt < 2; ++nt)
          ob[(size_t)(wb * 49 + row) * 256 + h * 32 + nt * 16 + lm] =
              __float2bfloat16(o[mt][nt][r] * inv[mt][r]);
      }
    }
}

// ---------------------------------------------------------------------------
// (B,HW,256) fp32 -> (B,256,HW) fp32 via 32x32 LDS tiles.
__global__ void k_transpose(const float* __restrict__ y, float* __restrict__ out) {
  __shared__ float t[32][33];
  int bb = blockIdx.z;
  int hw0 = blockIdx.x * 32;
  int o0 = blockIdx.y * 32;
  int tx = threadIdx.x, ty = threadIdx.y;  // 32 x 8
#pragma unroll
  for (int r = 0; r < 4; ++r)
    t[ty + r * 8][tx] = y[(size_t)(bb * 3136 + hw0 + ty + r * 8) * 256 + o0 + tx];
  __syncthreads();
#pragma unroll
  for (int r = 0; r < 4; ++r)
    out[(size_t)(bb * 256 + o0 + ty + r * 8) * 3136 + hw0 + tx] = t[tx][ty + r * 8];
}

// ---------------------------------------------------------------------------
extern "C" void kernel_launch(void* const* d_in, const int* in_sizes, int n_in,
                              void* d_out, int out_size, void* d_ws, size_t ws_size,
                              hipStream_t stream) {
  const float* x_edge = (const float*)d_in[0];
  const float* x_body = (const float*)d_in[1];
  const float* ne_w   = (const float*)d_in[2];
  const float* ne_b   = (const float*)d_in[3];
  const float* conv_w = (const float*)d_in[4];
  const float* n1_w   = (const float*)d_in[5];
  const float* n1_b   = (const float*)d_in[6];
  const float* rpb    = (const float*)d_in[7];
  const float* q_w    = (const float*)d_in[8];
  const float* kv_w   = (const float*)d_in[9];
  const float* proj_w = (const float*)d_in[10];
  const float* proj_b = (const float*)d_in[11];
  const float* n2_w   = (const float*)d_in[12];
  const float* n2_b   = (const float*)d_in[13];
  const float* fc1_w  = (const float*)d_in[14];
  const float* fc1_b  = (const float*)d_in[15];
  const float* fc2_w  = (const float*)d_in[16];
  const float* fc2_b  = (const float*)d_in[17];
  float* out = (float*)d_out;
  (void)in_sizes; (void)n_in; (void)out_size; (void)ws_size;

  // ---- workspace layout (explicit, overlap-audited) ----
  const size_t SZ_Ae    = (size_t)M_ * 128 * 2;   //  12,845,056
  const size_t SZ_bf256 = (size_t)M_ * 256 * 2;   //  25,690,112
  const size_t SZ_bf512 = (size_t)M_ * 512 * 2;   //  51,380,224
  const size_t SZ_h1    = (size_t)M_ * 1024 * 2;  // 102,760,448

  char* ws = (char*)d_ws;
  __hip_bfloat16* Wb = (__hip_bfloat16*)ws;            // 1,638,400 B (persists)
  float* part  = (float*)(ws + 1638400);               // 8 KB
  float* stats = (float*)(ws + 1638400 + 8192);        // 256 B
  float* biasp = (float*)(ws + 1638400 + 8192 + 256);  // 131,072 B (persists)
  char*  P     = ws + 1638400 + 8192 + 256 + 131072;   // pool base
  __hip_bfloat16* w_conv = Wb;
  __hip_bfloat16* w_q    = Wb + 32768;
  __hip_bfloat16* w_kv   = Wb + 98304;
  __hip_bfloat16* w_proj = Wb + 229376;
  __hip_bfloat16* w_fc1  = Wb + 294912;
  __hip_bfloat16* w_fc2  = Wb + 557056;
  // Phase-1 pool members (all dead by the fc1 GEMM):
  __hip_bfloat16* Ae    = (__hip_bfloat16*)(P);
  __hip_bfloat16* xbn   = (__hip_bfloat16*)(P + SZ_Ae);
  __hip_bfloat16* xec   = (__hip_bfloat16*)(P + SZ_Ae + SZ_bf256);
  __hip_bfloat16* qb    = (__hip_bfloat16*)(P + SZ_Ae + 2 * SZ_bf256);
  __hip_bfloat16* kvb   = (__hip_bfloat16*)(P + SZ_Ae + 3 * SZ_bf256);
  __hip_bfloat16* attnb = (__hip_bfloat16*)(P + SZ_Ae + 3 * SZ_bf256 + SZ_bf512);
  // h1 @ P+0; xn/yb @ tail (past h1 end); xf -> d_out (overwritten by transpose)
  __hip_bfloat16* h1 = (__hip_bfloat16*)(P);
  char* tail         = P + ((SZ_h1 + 1024 * 1024) & ~(size_t)1023);
  __hip_bfloat16* xn = (__hip_bfloat16*)tail;
  float*          yb = (float*)tail;
  float*          xf = (float*)d_out;

  const float qscale = 0.17677669529663687f;  // HD^-0.5

  k_cast6<<<800, 256, 0, stream>>>(conv_w, q_w, kv_w, proj_w, fc1_w, fc2_w, Wb);
  k_bias_pre<<<128, 64, 0, stream>>>(rpb, biasp);
  k_stats1<<<1024, 256, 0, stream>>>(x_edge, part);
  k_stats2<<<16, 64, 0, stream>>>(part, stats);
  k_prep_edge<<<1024, 256, 0, stream>>>(x_edge, ne_w, ne_b, stats, Ae);
  k_ln_rows<true><<<M_ / 4, 256, 0, stream>>>(x_body, n1_w, n1_b, xbn);
  gemm_bt<0><<<dim3(2, 392), 256, 0, stream>>>(Ae, w_conv, M_, 256, 128, xec, nullptr, nullptr, nullptr, 0.f);
  gemm_bt<1><<<dim3(2, 392), 256, 0, stream>>>(xec, w_q, M_, 256, 256, qb, nullptr, nullptr, nullptr, qscale);
  gemm_bt<0><<<dim3(4, 392), 256, 0, stream>>>(xbn, w_kv, M_, 512, 256, kvb, nullptr, nullptr, nullptr, 0.f);
  k_attn_mfma<<<8192, 64, 0, stream>>>(qb, kvb, biasp, attnb);
  gemm_bt<2><<<dim3(2, 392), 256, 0, stream>>>(attnb, w_proj, M_, 256, 256, nullptr, xf, proj_b, x_body, 0.f);
  k_ln_rows<false><<<M_ / 4, 256, 0, stream>>>(xf, n2_w, n2_b, xn);
  gemm_bt<3><<<dim3(8, 392), 256, 0, stream>>>(xn, w_fc1, M_, 1024, 256, h1, nullptr, fc1_b, nullptr, 0.f);
  gemm_bt<4><<<dim3(2, 392), 256, 0, stream>>>(h1, w_fc2, M_, 256, 1024, nullptr, yb, fc2_b, xf, 0.f);
  k_transpose<<<dim3(98, 8, 16), dim3(32, 8), 0, stream>>>(yb, out);
}

// Round 5
// 545.320 us; speedup vs baseline: 1.4794x; 1.0304x over previous
//
#include <hip/hip_runtime.h>
#include <hip/hip_bf16.h>
#include <math.h>

// Problem constants
#define B_    16
#define CE_   128
#define CB_   256
#define H_    56
#define W_    56
#define NH_   8
#define WS_   7
#define HD_   32
#define NWIN_ 49      // WS*WS
#define HW_   3136    // H*W
#define M_    50176   // B*H*W rows
#define HID_  1024

typedef short bf16x8 __attribute__((ext_vector_type(8)));
typedef float f32x4  __attribute__((ext_vector_type(4)));

__device__ __forceinline__ float waveRedSum(float v) {
#pragma unroll
  for (int off = 32; off; off >>= 1) v += __shfl_xor(v, off, 64);
  return v;
}

// Async global->LDS, 16B per lane.  LDS dest = wave-uniform base + lane*16.
__device__ __forceinline__ void load_lds16(const void* g, void* l) {
  __builtin_amdgcn_global_load_lds((__attribute__((address_space(1))) void*)g,
                                   (__attribute__((address_space(3))) void*)l,
                                   16, 0, 0);
}

// ---------------------------------------------------------------------------
// x_edge stats, stage 1: 1024 blocks (64 per batch), partial sums to ws.
__global__ void k_stats1(const float* __restrict__ xe, float* __restrict__ part) {
  int blk = blockIdx.x;
  int b = blk >> 6, s = blk & 63;
  const float4* p = (const float4*)(xe + (size_t)b * 401408 + s * 6272);
  float sm = 0.f, s2 = 0.f;
  for (int i = threadIdx.x; i < 1568; i += 256) {
    float4 v = p[i];
    sm += v.x + v.y + v.z + v.w;
    s2 += v.x * v.x + v.y * v.y + v.z * v.z + v.w * v.w;
  }
  sm = waveRedSum(sm); s2 = waveRedSum(s2);
  __shared__ float aux[8];
  int wave = threadIdx.x >> 6, lane = threadIdx.x & 63;
  if (lane == 0) { aux[wave] = sm; aux[4 + wave] = s2; }
  __syncthreads();
  if (threadIdx.x == 0) {
    part[blk * 2]     = aux[0] + aux[1] + aux[2] + aux[3];
    part[blk * 2 + 1] = aux[4] + aux[5] + aux[6] + aux[7];
  }
}

// stage 2: 16 blocks x 64 threads -> mean/rstd per batch.
__global__ void k_stats2(const float* __restrict__ part, float* __restrict__ stats) {
  int b = blockIdx.x, lane = threadIdx.x;
  float sm = part[(b * 64 + lane) * 2];
  float s2 = part[(b * 64 + lane) * 2 + 1];
  sm = waveRedSum(sm); s2 = waveRedSum(s2);
  if (lane == 0) {
    float mean = sm / 401408.0f;
    float var  = s2 / 401408.0f - mean * mean;
    stats[b * 2] = mean;
    stats[b * 2 + 1] = rsqrtf(var + 1e-5f);
  }
}

// ---------------------------------------------------------------------------
// Cast weight matrices fp32 -> bf16 into one contiguous buffer.
__global__ void k_cast6(const float* __restrict__ s0, const float* __restrict__ s1,
                        const float* __restrict__ s2, const float* __restrict__ s3,
                        const float* __restrict__ s4, const float* __restrict__ s5,
                        __hip_bfloat16* __restrict__ d) {
  size_t i4 = ((size_t)blockIdx.x * 256 + threadIdx.x) * 4;
  if (i4 >= 819200) return;
  const float* src; size_t off;
  if      (i4 < 32768)  { src = s0; off = 0; }
  else if (i4 < 98304)  { src = s1; off = 32768; }
  else if (i4 < 229376) { src = s2; off = 98304; }
  else if (i4 < 294912) { src = s3; off = 229376; }
  else if (i4 < 557056) { src = s4; off = 294912; }
  else                  { src = s5; off = 557056; }
  float4 v = *(const float4*)(src + (i4 - off));
  union { __hip_bfloat16 h[4]; uint2 u; } pk;
  pk.h[0] = __float2bfloat16(v.x);
  pk.h[1] = __float2bfloat16(v.y);
  pk.h[2] = __float2bfloat16(v.z);
  pk.h[3] = __float2bfloat16(v.w);
  *(uint2*)(d + i4) = pk.u;
}

// ---------------------------------------------------------------------------
// W_qc = qscale * q_w(256x256) @ conv_w(256x128) -> bf16 (256x128 row-major).
// Folds the 1x1 conv into the Q projection (xec eliminated).
// 256 blocks x 128 threads; q_w row access is block-uniform (scalarized).
__global__ void k_wqc(const float* __restrict__ qw, const float* __restrict__ cw,
                      __hip_bfloat16* __restrict__ wqc) {
  int o2 = blockIdx.x, c = threadIdx.x;
  float acc = 0.f;
#pragma unroll 4
  for (int o = 0; o < 256; ++o)
    acc += qw[o2 * 256 + o] * cw[o * 128 + c];
  wqc[o2 * 128 + c] = __float2bfloat16(acc * 0.17677669529663687f);
}

// ---------------------------------------------------------------------------
// Precompute rel-pos bias in MFMA C-fragment order + padding mask.
__global__ void k_bias_pre(const float* __restrict__ rpb, float* __restrict__ bp) {
  int blk = blockIdx.x;         // h*16 + ti*4 + tj
  int h = blk >> 4, tile = blk & 15;
  int ti = tile >> 2, tj = tile & 3;
  int lane = threadIdx.x;
  int quad = lane >> 4, lm = lane & 15;
  float4 v;
  float* vp = (float*)&v;
#pragma unroll
  for (int r = 0; r < 4; ++r) {
    int i = ti * 16 + quad * 4 + r;
    int j = tj * 16 + lm;
    float b = -1e30f;
    if (i < 49 && j < 49) {
      int rel = (i / 7 - j / 7 + 6) * 13 + (i % 7 - j % 7 + 6);
      b = rpb[rel * 8 + h];
    }
    vp[r] = b;
  }
  *(float4*)&bp[(size_t)(blk * 64 + lane) * 4] = v;
}

// ---------------------------------------------------------------------------
// Normalize x_edge (per-element affine), emit bf16 A matrix in WINDOWED row
// order: row m = wb*49 + p, cols = 128 channels.  1024 blocks (one/window).
__global__ void k_prep_edge(const float* __restrict__ xe,
                            const float* __restrict__ we,
                            const float* __restrict__ be,
                            const float* __restrict__ stats,
                            __hip_bfloat16* __restrict__ Ae) {
  int wb = blockIdx.x;
  int b = wb >> 6, rem = wb & 63;
  int h0 = (rem >> 3) * 7, w0 = (rem & 7) * 7;
  float mean = stats[b * 2], rstd = stats[b * 2 + 1];
  __shared__ __hip_bfloat16 t[49 * 130];
  for (int idx = threadIdx.x; idx < 128 * 49; idx += 256) {
    int c = idx / 49, p = idx % 49;
    int h = h0 + p / 7, w = w0 + p % 7;
    int off = (c * 56 + h) * 56 + w;
    float v = xe[(size_t)b * 401408 + off];
    t[p * 130 + c] = __float2bfloat16((v - mean) * rstd * we[off] + be[off]);
  }
  __syncthreads();
  __hip_bfloat16* dst = Ae + (size_t)wb * 49 * 128;
  for (int idx = threadIdx.x; idx < 49 * 128; idx += 256) {
    int p = idx >> 7, c = idx & 127;
    dst[idx] = t[p * 130 + c];
  }
}

// ---------------------------------------------------------------------------
// Row LayerNorm over 256 channels; one wave per row, 4 rows/block.
template <bool PERM>
__global__ void k_ln_rows(const float* __restrict__ x,
                          const float* __restrict__ w,
                          const float* __restrict__ bia,
                          __hip_bfloat16* __restrict__ out) {
  int row = blockIdx.x * 4 + (threadIdx.x >> 6);
  int lane = threadIdx.x & 63;
  float4 xv = *(const float4*)(x + (size_t)row * 256 + lane * 4);
  float s  = xv.x + xv.y + xv.z + xv.w;
  float s2 = xv.x * xv.x + xv.y * xv.y + xv.z * xv.z + xv.w * xv.w;
  s = waveRedSum(s); s2 = waveRedSum(s2);
  float mean = s * (1.0f / 256.0f);
  float var  = s2 * (1.0f / 256.0f) - mean * mean;
  float rstd = rsqrtf(var + 1e-5f);
  int orow = row;
  if (PERM) {
    int b = row / 3136, hw = row % 3136;
    int h = hw / 56, ww = hw % 56;
    orow = (b * 64 + (h / 7) * 8 + (ww / 7)) * 49 + (h % 7) * 7 + (ww % 7);
  }
  float4 wv = *(const float4*)(w + lane * 4);
  float4 bv = *(const float4*)(bia + lane * 4);
  union { __hip_bfloat16 h[4]; uint2 u; } pk;
  pk.h[0] = __float2bfloat16((xv.x - mean) * rstd * wv.x + bv.x);
  pk.h[1] = __float2bfloat16((xv.y - mean) * rstd * wv.y + bv.y);
  pk.h[2] = __float2bfloat16((xv.z - mean) * rstd * wv.z + bv.z);
  pk.h[3] = __float2bfloat16((xv.w - mean) * rstd * wv.w + bv.w);
  *(uint2*)(out + (size_t)orow * 256 + lane * 4) = pk.u;
}

// ---------------------------------------------------------------------------
// MFMA GEMM:  C(MxN) = A(MxK,bf16) * W(NxK,bf16)^T   with epilogues.
// 128x128 tile, BK=32, 256 threads.  1-D grid of 392*NX blocks with
// XCD-aware swizzle: xcd=lin&7 owns m-bands [xcd*49, xcd*49+49), sweeping
// the NX n-tiles of a band consecutively (A-tile stays in that XCD's L2).
// EPI: 0 store bf16 | 2 proj(+bias+resid, permute rows, f32)
//      3 bias+gelu(tanh) bf16 | 4 bias+resid f32
template <int EPI, int NX>
__launch_bounds__(256)
__global__ void gemm_bt(const __hip_bfloat16* __restrict__ A,
                        const __hip_bfloat16* __restrict__ Bw,
                        int M, int N, int K,
                        __hip_bfloat16* __restrict__ outb,
                        float* __restrict__ outf,
                        const float* __restrict__ bias,
                        const float* __restrict__ resid) {
  __shared__ __hip_bfloat16 As[4 * 128 * 8];  // 8 KB
  __shared__ __hip_bfloat16 Bs[4 * 128 * 8];  // 8 KB
  const int tid  = threadIdx.x;
  const int lane = tid & 63;
  const int wave = tid >> 6;
  const int quad = lane >> 4;
  const int lm   = lane & 15;
  const int wm   = (wave & 1) << 6;
  const int wn   = (wave >> 1) << 6;
  // XCD-aware swizzle (392 bands = 8 XCDs x 49)
  const int lin  = blockIdx.x;
  const int slot = lin >> 3;
  const int band = (lin & 7) * 49 + slot / NX;
  const int n0   = (slot % NX) * 128;
  const int m0   = band * 128;

  const int rh = (wave & 1) * 64;   // row-half base
  const int qw = wave >> 1;         // base k-quad
  const __hip_bfloat16* Arow = A  + (size_t)(m0 + rh + lane) * K;
  const __hip_bfloat16* Brow = Bw + (size_t)(n0 + rh + lane) * K;

  f32x4 acc[4][4];
#pragma unroll
  for (int i = 0; i < 4; ++i)
#pragma unroll
    for (int j = 0; j < 4; ++j)
#pragma unroll
      for (int r = 0; r < 4; ++r) acc[i][j][r] = 0.f;

  for (int k0 = 0; k0 < K; k0 += 32) {
#pragma unroll
    for (int p = 0; p < 2; ++p) {
      int q = qw + 2 * p;
      load_lds16(Arow + k0 + q * 8, &As[(q * 128 + rh) * 8]);
      load_lds16(Brow + k0 + q * 8, &Bs[(q * 128 + rh) * 8]);
    }
    __syncthreads();
    bf16x8 af[4], bfr[4];
#pragma unroll
    for (int i = 0; i < 4; ++i)
      af[i] = *(const bf16x8*)&As[(quad * 128 + wm + i * 16 + lm) * 8];
#pragma unroll
    for (int j = 0; j < 4; ++j)
      bfr[j] = *(const bf16x8*)&Bs[(quad * 128 + wn + j * 16 + lm) * 8];
#pragma unroll
    for (int i = 0; i < 4; ++i)
#pragma unroll
      for (int j = 0; j < 4; ++j)
        acc[i][j] = __builtin_amdgcn_mfma_f32_16x16x32_bf16(af[i], bfr[j], acc[i][j], 0, 0, 0);
    __syncthreads();
  }

  // epilogue: loops ordered i->r->j so row-derived values (gm, nat) hoist
#pragma unroll
  for (int i = 0; i < 4; ++i) {
#pragma unroll
    for (int r = 0; r < 4; ++r) {
      int gm = m0 + wm + i * 16 + quad * 4 + r;
      size_t rowbase;
      if constexpr (EPI == 2) {
        int wb = gm / 49, nn = gm % 49;
        int b = wb >> 6, rem = wb & 63;
        int h = (rem >> 3) * 7 + nn / 7, w = (rem & 7) * 7 + nn % 7;
        rowbase = (size_t)(b * 3136 + h * 56 + w) * 256;
      } else {
        rowbase = (size_t)gm * N;
      }
#pragma unroll
      for (int j = 0; j < 4; ++j) {
        int gn = n0 + wn + j * 16 + lm;
        float v = acc[i][j][r];
        if constexpr (EPI == 0) {
          outb[rowbase + gn] = __float2bfloat16(v);
        } else if constexpr (EPI == 2) {
          outf[rowbase + gn] = v + bias[gn] + resid[rowbase + gn];
        } else if constexpr (EPI == 3) {
          float x = v + bias[gn];
          float y = 0.7978845608028654f * (x + 0.044715f * x * x * x);
          float e = __expf(2.0f * y);
          float th = 1.0f - 2.0f / (e + 1.0f);
          outb[rowbase + gn] = __float2bfloat16(0.5f * x * (1.0f + th));
        } else {  // EPI == 4
          outf[rowbase + gn] = v + bias[gn] + resid[rowbase + gn];
        }
      }
    }
  }
}

// ---------------------------------------------------------------------------
// MFMA windowed attention: one WAVE per (window, head).  8192 blocks x 64 thr.
__launch_bounds__(64)
__global__ void k_attn_mfma(const __hip_bfloat16* __restrict__ qb,
                            const __hip_bfloat16* __restrict__ kvb,
                            const float* __restrict__ bp,
                            __hip_bfloat16* __restrict__ ob) {
  int wb = blockIdx.x >> 3;
  int h  = blockIdx.x & 7;
  __shared__ __align__(16) __hip_bfloat16 lds[7424];
  __hip_bfloat16* Qs = lds;
  __hip_bfloat16* Ks = lds + 2560;
  __hip_bfloat16* Vt = lds + 5120;
  __hip_bfloat16* Ps = lds;
  const int lane = threadIdx.x;
  const int quad = lane >> 4, lm = lane & 15;

  const __hip_bfloat16 zb = __float2bfloat16(0.f);
  for (int i = lane; i < 600; i += 64) { Qs[1960 + i] = zb; Ks[1960 + i] = zb; }
  {
    uint4 z; z.x = z.y = z.z = z.w = 0u;
    for (int i = lane; i < 288; i += 64) ((uint4*)Vt)[i] = z;
  }
  {
    int t = lane >> 2, p = lane & 3;
#pragma unroll
    for (int pass = 0; pass < 4; ++pass, t += 16) {
      if (t < 49) {
        size_t rq = (size_t)(wb * 49 + t);
        uint4 qv = *(const uint4*)(qb + rq * 256 + h * 32 + p * 8);
        *(uint4*)&Qs[t * 40 + p * 8] = qv;
        uint4 kv = *(const uint4*)(kvb + rq * 512 + h * 32 + p * 8);
        *(uint4*)&Ks[t * 40 + p * 8] = kv;
        union { uint4 u; __hip_bfloat16 e[8]; } vv;
        vv.u = *(const uint4*)(kvb + rq * 512 + 256 + h * 32 + p * 8);
#pragma unroll
        for (int i = 0; i < 8; ++i) Vt[(p * 8 + i) * 72 + t] = vv.e[i];
      }
    }
  }
  __builtin_amdgcn_s_waitcnt(0);

  bf16x8 qf[4], kf[4];
#pragma unroll
  for (int i = 0; i < 4; ++i) qf[i] = *(const bf16x8*)&Qs[(i * 16 + lm) * 40 + quad * 8];
#pragma unroll
  for (int j = 0; j < 4; ++j) kf[j] = *(const bf16x8*)&Ks[(j * 16 + lm) * 40 + quad * 8];
  f32x4 s[4][4];
#pragma unroll
  for (int i = 0; i < 4; ++i)
#pragma unroll
    for (int j = 0; j < 4; ++j) {
      f32x4 z4; z4[0] = z4[1] = z4[2] = z4[3] = 0.f;
      s[i][j] = __builtin_amdgcn_mfma_f32_16x16x32_bf16(qf[i], kf[j], z4, 0, 0, 0);
    }
#pragma unroll
  for (int ti = 0; ti < 4; ++ti)
#pragma unroll
    for (int tj = 0; tj < 4; ++tj) {
      f32x4 b = *(const f32x4*)&bp[(size_t)(((h * 4 + ti) * 4 + tj) * 64 + lane) * 4];
      s[ti][tj] += b;
    }
  float mrow[4][4], srow[4][4];
#pragma unroll
  for (int ti = 0; ti < 4; ++ti)
#pragma unroll
    for (int r = 0; r < 4; ++r)
      mrow[ti][r] = fmaxf(fmaxf(s[ti][0][r], s[ti][1][r]), fmaxf(s[ti][2][r], s[ti][3][r]));
#pragma unroll
  for (int mask = 1; mask <= 8; mask <<= 1)
#pragma unroll
    for (int ti = 0; ti < 4; ++ti)
#pragma unroll
      for (int r = 0; r < 4; ++r)
        mrow[ti][r] = fmaxf(mrow[ti][r], __shfl_xor(mrow[ti][r], mask, 64));
#pragma unroll
  for (int ti = 0; ti < 4; ++ti)
#pragma unroll
    for (int tj = 0; tj < 4; ++tj)
#pragma unroll
      for (int r = 0; r < 4; ++r)
        s[ti][tj][r] = __expf(s[ti][tj][r] - mrow[ti][r]);
#pragma unroll
  for (int ti = 0; ti < 4; ++ti)
#pragma unroll
    for (int r = 0; r < 4; ++r)
      srow[ti][r] = s[ti][0][r] + s[ti][1][r] + s[ti][2][r] + s[ti][3][r];
#pragma unroll
  for (int mask = 1; mask <= 8; mask <<= 1)
#pragma unroll
    for (int ti = 0; ti < 4; ++ti)
#pragma unroll
      for (int r = 0; r < 4; ++r)
        srow[ti][r] += __shfl_xor(srow[ti][r], mask, 64);
  float inv[4][4];
#pragma unroll
  for (int ti = 0; ti < 4; ++ti)
#pragma unroll
    for (int r = 0; r < 4; ++r)
      inv[ti][r] = 1.0f / srow[ti][r];

#pragma unroll
  for (int ti = 0; ti < 4; ++ti)
#pragma unroll
    for (int tj = 0; tj < 4; ++tj)
#pragma unroll
      for (int r = 0; r < 4; ++r)
        Ps[(ti * 16 + quad * 4 + r) * 72 + tj * 16 + lm] = __float2bfloat16(s[ti][tj][r]);
  __builtin_amdgcn_s_waitcnt(0);

  f32x4 o[4][2];
#pragma unroll
  for (int mt = 0; mt < 4; ++mt)
#pragma unroll
    for (int nt = 0; nt < 2; ++nt)
#pragma unroll
      for (int r = 0; r < 4; ++r) o[mt][nt][r] = 0.f;
#pragma unroll
  for (int kq = 0; kq < 2; ++kq) {
    bf16x8 pa[4], vb[2];
#pragma unroll
    for (int mt = 0; mt < 4; ++mt)
      pa[mt] = *(const bf16x8*)&Ps[(mt * 16 + lm) * 72 + kq * 32 + quad * 8];
#pragma unroll
    for (int nt = 0; nt < 2; ++nt)
      vb[nt] = *(const bf16x8*)&Vt[(nt * 16 + lm) * 72 + kq * 32 + quad * 8];
#pragma unroll
    for (int mt = 0; mt < 4; ++mt)
#pragma unroll
      for (int nt = 0; nt < 2; ++nt)
        o[mt][nt] = __builtin_amdgcn_mfma_f32_16x16x32_bf16(pa[mt], vb[nt], o[mt][nt], 0, 0, 0);
  }
#pragma unroll
  for (int mt = 0; mt < 4; ++mt)
#pragma unroll
    for (int r = 0; r < 4; ++r) {
      int row = mt * 16 + quad * 4 + r;
      if (row < 49) {
#pragma unroll
        for (int nt = 0; nt < 2; ++nt)
          ob[(size_t)(wb * 49 + row) * 256 + h * 32 + nt * 16 + lm] =
              __float2bfloat16(o[mt][nt][r] * inv[mt][r]);
      }
    }
}

// ---------------------------------------------------------------------------
// (B,HW,256) fp32 -> (B,256,HW) fp32 via 32x32 LDS tiles.
__global__ void k_transpose(const float* __restrict__ y, float* __restrict__ out) {
  __shared__ float t[32][33];
  int bb = blockIdx.z;
  int hw0 = blockIdx.x * 32;
  int o0 = blockIdx.y * 32;
  int tx = threadIdx.x, ty = threadIdx.y;  // 32 x 8
#pragma unroll
  for (int r = 0; r < 4; ++r)
    t[ty + r * 8][tx] = y[(size_t)(bb * 3136 + hw0 + ty + r * 8) * 256 + o0 + tx];
  __syncthreads();
#pragma unroll
  for (int r = 0; r < 4; ++r)
    out[(size_t)(bb * 256 + o0 + ty + r * 8) * 3136 + hw0 + tx] = t[tx][ty + r * 8];
}

// ---------------------------------------------------------------------------
extern "C" void kernel_launch(void* const* d_in, const int* in_sizes, int n_in,
                              void* d_out, int out_size, void* d_ws, size_t ws_size,
                              hipStream_t stream) {
  const float* x_edge = (const float*)d_in[0];
  const float* x_body = (const float*)d_in[1];
  const float* ne_w   = (const float*)d_in[2];
  const float* ne_b   = (const float*)d_in[3];
  const float* conv_w = (const float*)d_in[4];
  const float* n1_w   = (const float*)d_in[5];
  const float* n1_b   = (const float*)d_in[6];
  const float* rpb    = (const float*)d_in[7];
  const float* q_w    = (const float*)d_in[8];
  const float* kv_w   = (const float*)d_in[9];
  const float* proj_w = (const float*)d_in[10];
  const float* proj_b = (const float*)d_in[11];
  const float* n2_w   = (const float*)d_in[12];
  const float* n2_b   = (const float*)d_in[13];
  const float* fc1_w  = (const float*)d_in[14];
  const float* fc1_b  = (const float*)d_in[15];
  const float* fc2_w  = (const float*)d_in[16];
  const float* fc2_b  = (const float*)d_in[17];
  float* out = (float*)d_out;
  (void)in_sizes; (void)n_in; (void)out_size; (void)ws_size;

  // ---- workspace layout (explicit, overlap-audited) ----
  const size_t SZ_Ae    = (size_t)M_ * 128 * 2;   //  12,845,056
  const size_t SZ_bf256 = (size_t)M_ * 256 * 2;   //  25,690,112
  const size_t SZ_bf512 = (size_t)M_ * 512 * 2;   //  51,380,224
  const size_t SZ_h1    = (size_t)M_ * 1024 * 2;  // 102,760,448

  char* ws = (char*)d_ws;
  __hip_bfloat16* Wb  = (__hip_bfloat16*)ws;                     // 1,638,400 B
  float* part  = (float*)(ws + 1638400);                         // 8 KB
  float* stats = (float*)(ws + 1638400 + 8192);                  // 256 B
  float* biasp = (float*)(ws + 1638400 + 8192 + 256);            // 131,072 B
  __hip_bfloat16* wqc = (__hip_bfloat16*)(ws + 1638400 + 8192 + 256 + 131072);  // 65,536 B
  char*  P     = ws + 1638400 + 8192 + 256 + 131072 + 65536;     // pool base
  __hip_bfloat16* w_kv   = Wb + 98304;
  __hip_bfloat16* w_proj = Wb + 229376;
  __hip_bfloat16* w_fc1  = Wb + 294912;
  __hip_bfloat16* w_fc2  = Wb + 557056;
  // Phase-1 pool (all dead by the fc1 GEMM):  xec eliminated (conv folded into q)
  __hip_bfloat16* Ae    = (__hip_bfloat16*)(P);
  __hip_bfloat16* xbn   = (__hip_bfloat16*)(P + SZ_Ae);
  __hip_bfloat16* qb    = (__hip_bfloat16*)(P + SZ_Ae + SZ_bf256);
  __hip_bfloat16* kvb   = (__hip_bfloat16*)(P + SZ_Ae + 2 * SZ_bf256);
  __hip_bfloat16* attnb = (__hip_bfloat16*)(P + SZ_Ae + 2 * SZ_bf256 + SZ_bf512);
  // h1 @ P+0 (everything above dead by fc1); xn/yb @ tail (past h1 end);
  // xf -> d_out (overwritten by final transpose)
  __hip_bfloat16* h1 = (__hip_bfloat16*)(P);
  char* tail         = P + ((SZ_h1 + 1024 * 1024) & ~(size_t)1023);
  __hip_bfloat16* xn = (__hip_bfloat16*)tail;
  float*          yb = (float*)tail;
  float*          xf = (float*)d_out;

  k_cast6<<<800, 256, 0, stream>>>(conv_w, q_w, kv_w, proj_w, fc1_w, fc2_w, Wb);
  k_wqc<<<256, 128, 0, stream>>>(q_w, conv_w, wqc);
  k_bias_pre<<<128, 64, 0, stream>>>(rpb, biasp);
  k_stats1<<<1024, 256, 0, stream>>>(x_edge, part);
  k_stats2<<<16, 64, 0, stream>>>(part, stats);
  k_prep_edge<<<1024, 256, 0, stream>>>(x_edge, ne_w, ne_b, stats, Ae);
  k_ln_rows<true><<<M_ / 4, 256, 0, stream>>>(x_body, n1_w, n1_b, xbn);
  // q = Ae @ W_qc^T (conv folded in, scale folded in)
  gemm_bt<0, 2><<<784, 256, 0, stream>>>(Ae, wqc, M_, 256, 128, qb, nullptr, nullptr, nullptr);
  // kv = xbn @ kv_w^T
  gemm_bt<0, 4><<<1568, 256, 0, stream>>>(xbn, w_kv, M_, 512, 256, kvb, nullptr, nullptr, nullptr);
  k_attn_mfma<<<8192, 64, 0, stream>>>(qb, kvb, biasp, attnb);
  // proj + bias + residual(x_body), windowed->natural rows, fp32 -> d_out (xf)
  gemm_bt<2, 2><<<784, 256, 0, stream>>>(attnb, w_proj, M_, 256, 256, nullptr, xf, proj_b, x_body);
  k_ln_rows<false><<<M_ / 4, 256, 0, stream>>>(xf, n2_w, n2_b, xn);
  // fc1 + bias + gelu(tanh)
  gemm_bt<3, 8><<<3136, 256, 0, stream>>>(xn, w_fc1, M_, 1024, 256, h1, nullptr, fc1_b, nullptr);
  // fc2 + bias + residual(xf)
  gemm_bt<4, 2><<<784, 256, 0, stream>>>(h1, w_fc2, M_, 256, 1024, nullptr, yb, fc2_b, xf);
  k_transpose<<<dim3(98, 8, 16), dim3(32, 8), 0, stream>>>(yb, out);
}